// Round 5
// baseline (307.086 us; speedup 1.0000x reference)
//
#include <hip/hip_runtime.h>
#include <hip/hip_bf16.h>
#include <stdint.h>

// Problem constants (from reference)
#define O_DIM   4096
#define I_DIM   2048
#define M_DENSE 8192
#define K_DENSE 4096
#define N_TOK   4096
#define K_ACT   2048

typedef __bf16 bf16x8 __attribute__((ext_vector_type(8)));
typedef float  f32x4  __attribute__((ext_vector_type(4)));

// round-to-nearest-even fp32 -> bf16 bits
__device__ __forceinline__ unsigned f2bf(float f) {
    unsigned u = __builtin_bit_cast(unsigned, f);
    return (u + 0x7FFFu + ((u >> 16) & 1u)) >> 16;
}

// async global->LDS, 16 bytes per lane; LDS dest = wave-uniform base + lane*16
__device__ __forceinline__ void load16(const unsigned short* g, unsigned short* l) {
    __builtin_amdgcn_global_load_lds(
        (__attribute__((address_space(1))) void*)(g),
        (__attribute__((address_space(3))) void*)(l),
        16, 0, 0);
}

// Merged prep: blocks [0,O_DIM) decompress weights, blocks [O_DIM, O_DIM+4096) cast input.
__global__ __launch_bounds__(256) void prep(const float* __restrict__ weight,
                                            const int* __restrict__ metadata,
                                            const int* __restrict__ idx,
                                            const float* __restrict__ input,
                                            uint4* __restrict__ A2,
                                            uint4* __restrict__ Bbt) {
    if (blockIdx.x >= O_DIM) {
        // ---- cast branch: fp32 [N_TOK x K_ACT] -> bf16 bits (B^T layout) ----
        int gid = (blockIdx.x - O_DIM) * 256 + threadIdx.x;  // 4096 blocks
        const float4* in = (const float4*)input;
        float4 a = in[2 * gid], b = in[2 * gid + 1];
        uint4 u;
        u.x = f2bf(a.x) | (f2bf(a.y) << 16);
        u.y = f2bf(a.z) | (f2bf(a.w) << 16);
        u.z = f2bf(b.x) | (f2bf(b.y) << 16);
        u.w = f2bf(b.z) | (f2bf(b.w) << 16);
        Bbt[gid] = u;
        return;
    }
    // ---- decompress branch: A2[o][j] = weight value for active col idx[j] ----
    __shared__ int   smeta[I_DIM];
    __shared__ float sw[I_DIM];
    int o = blockIdx.x;
    const int4*   mrow = (const int4*)(metadata + (size_t)o * I_DIM);
    const float4* wrow = (const float4*)(weight + (size_t)o * I_DIM);
#pragma unroll
    for (int it = 0; it < I_DIM / 4 / 256; ++it) {
        int i = it * 256 + threadIdx.x;
        *(int4*)(smeta + i * 4) = mrow[i];
        *(float4*)(sw + i * 4)  = wrow[i];
    }
    __syncthreads();
    int j0 = threadIdx.x * 8;                            // 256 threads * 8 = K_ACT
    int4 c0 = *(const int4*)(idx + j0);
    int4 c1 = *(const int4*)(idx + j0 + 4);
    int cs[8] = {c0.x, c0.y, c0.z, c0.w, c1.x, c1.y, c1.z, c1.w};
    unsigned r[8];
#pragma unroll
    for (int u = 0; u < 8; ++u) {
        int c = cs[u];
        int g2 = (c >> 2) * 2;
        int pos = c & 3;
        int m0v = smeta[g2], m1v = smeta[g2 + 1];
        float v = (m0v == pos) ? sw[g2] : ((m1v == pos) ? sw[g2 + 1] : 0.0f);
        r[u] = f2bf(v);
    }
    uint4 packed;
    packed.x = r[0] | (r[1] << 16);
    packed.y = r[2] | (r[3] << 16);
    packed.z = r[4] | (r[5] << 16);
    packed.w = r[6] | (r[7] << 16);
    A2[((size_t)o * K_ACT + j0) >> 3] = packed;
}

// GEMM: C[o][t] = sum_j A2[o][j] * Bt[t][j]; rows scattered to out[indices[o]].
// M=4096, N=4096, K=2048. 128x128 tile, BK=64 (32 MFMA per barrier pair,
// AITER-like density; halves barrier count vs BK=32), 4 waves, 16x16x32 MFMA.
// LDS rows are 128B: k-segments XOR-swizzled by row&7 so quad-lane ds_read_b128
// spreads over all banks (unswizzled would be 16-way conflict at this stride).
// Prologue zeroes this block's share of the INACTIVE dense output rows.
__global__ __launch_bounds__(256, 4) void gemm_scatter(
        const unsigned short* __restrict__ A,
        const unsigned short* __restrict__ Bt,
        const int* __restrict__ indices,
        float* __restrict__ out) {
    constexpr int N = N_TOK, K = K_ACT;
    constexpr int TM = 128, TN = 128, BK = 64;
    __shared__ alignas(16) unsigned short sA[TM * BK];   // 16 KB
    __shared__ alignas(16) unsigned short sB[TN * BK];   // 16 KB
    __shared__ int s_list[256];
    __shared__ int s_cnt;

    const int t    = threadIdx.x;       // 0..255
    const int wave = t >> 6;            // 0..3
    const int lane = t & 63;
    const int m0 = blockIdx.y * TM;
    const int n0 = blockIdx.x * TN;

    // ---- zero this block's inactive-row slice (rows [by*256,+256) x cols [bx*128,+128)) ----
    {
        if (t == 0) s_cnt = 0;
        int r = blockIdx.y * 256 + t;                    // dense row
        int lo = 0, hi = O_DIM;
        while (lo < hi) { int mid = (lo + hi) >> 1; if (indices[mid] < r) lo = mid + 1; else hi = mid; }
        bool inactive = !(lo < O_DIM && indices[lo] == r);
        __syncthreads();
        if (inactive) { int p = atomicAdd(&s_cnt, 1); s_list[p] = r; }
        __syncthreads();
        int nin = s_cnt;
        float4 z4 = {0.f, 0.f, 0.f, 0.f};
        for (int task = t; task < nin * 32; task += 256) {
            int row = s_list[task >> 5];
            int c4  = task & 31;                         // 32 float4 = 128 cols
            *(float4*)(out + (size_t)row * N + n0 + c4 * 4) = z4;
        }
    }

    // staging: chunk f = q*256 + t (q=0..3) covers LDS elements [f*8, f*8+8)
    // = row (f>>3), physical k-seg (f&7). Physical slot s of row r holds
    // global k-seg s^(r&7)  ->  source offset below.
    const unsigned short* gA[4];
    const unsigned short* gB[4];
#pragma unroll
    for (int q = 0; q < 4; ++q) {
        int f = q * 256 + t;
        int r = f >> 3, s = (f & 7) ^ (r & 7);
        gA[q] = A  + (size_t)(m0 + r) * K + s * 8;
        gB[q] = Bt + (size_t)(n0 + r) * K + s * 8;
    }
    // wave-uniform LDS bases (elements): q*2048 + wave*512
    unsigned short* lA[4];
    unsigned short* lB[4];
#pragma unroll
    for (int q = 0; q < 4; ++q) {
        lA[q] = sA + q * 2048 + wave * 512;
        lB[q] = sB + q * 2048 + wave * 512;
    }

    const int wm   = (wave >> 1) * 64;  // wave's 64x64 quadrant
    const int wn   = (wave & 1) * 64;
    const int quad = lane >> 4;
    const int lr   = lane & 15;
    const int lr7  = lr & 7;
    // row bases (wm, mi*16) are multiples of 8 -> row&7 == lr&7.
    // global k-seg quad  (k 0..31) -> phys slot s0 = quad^lr7
    // global k-seg quad|4 (k 32..63) -> phys slot s0^4
    const int k0 = (quad ^ lr7) * 8;
    const int k1 = k0 ^ 32;

    f32x4 acc[4][4] = {};

    for (int kk = 0; kk < K; kk += BK) {
        __syncthreads();   // previous compute done before overwriting LDS
#pragma unroll
        for (int q = 0; q < 4; ++q) load16(gA[q] + kk, lA[q]);
#pragma unroll
        for (int q = 0; q < 4; ++q) load16(gB[q] + kk, lB[q]);
        __syncthreads();   // drains vmcnt before barrier

        bf16x8 af[4], bf[4];
        // ---- k-half 0 ----
#pragma unroll
        for (int mi = 0; mi < 4; ++mi)
            af[mi] = *(const bf16x8*)(sA + (wm + mi * 16 + lr) * BK + k0);
#pragma unroll
        for (int ni = 0; ni < 4; ++ni)
            bf[ni] = *(const bf16x8*)(sB + (wn + ni * 16 + lr) * BK + k0);
#pragma unroll
        for (int mi = 0; mi < 4; ++mi)
#pragma unroll
            for (int ni = 0; ni < 4; ++ni)
                acc[mi][ni] = __builtin_amdgcn_mfma_f32_16x16x32_bf16(
                    af[mi], bf[ni], acc[mi][ni], 0, 0, 0);
        // ---- k-half 1 ----
#pragma unroll
        for (int mi = 0; mi < 4; ++mi)
            af[mi] = *(const bf16x8*)(sA + (wm + mi * 16 + lr) * BK + k1);
#pragma unroll
        for (int ni = 0; ni < 4; ++ni)
            bf[ni] = *(const bf16x8*)(sB + (wn + ni * 16 + lr) * BK + k1);
#pragma unroll
        for (int mi = 0; mi < 4; ++mi)
#pragma unroll
            for (int ni = 0; ni < 4; ++ni)
                acc[mi][ni] = __builtin_amdgcn_mfma_f32_16x16x32_bf16(
                    af[mi], bf[ni], acc[mi][ni], 0, 0, 0);
    }

    // epilogue: D lane layout col=lane&15, row=quad*4+reg (m91-verified)
#pragma unroll
    for (int mi = 0; mi < 4; ++mi) {
#pragma unroll
        for (int r = 0; r < 4; ++r) {
            int gm = m0 + wm + mi * 16 + quad * 4 + r;
            int orow = indices[gm];
            float* op = out + (size_t)orow * N + n0 + wn + lr;
#pragma unroll
            for (int ni = 0; ni < 4; ++ni)
                op[ni * 16] = acc[mi][ni][r];
        }
    }
}

extern "C" void kernel_launch(void* const* d_in, const int* in_sizes, int n_in,
                              void* d_out, int out_size, void* d_ws, size_t ws_size,
                              hipStream_t stream) {
    const float* input    = (const float*)d_in[0];
    const int*   idx      = (const int*)d_in[1];
    const float* weight   = (const float*)d_in[2];
    const int*   indices  = (const int*)d_in[3];
    const int*   metadata = (const int*)d_in[4];
    float* out = (float*)d_out;

    // workspace layout: A2 (16 MB) | Bbt (16 MB)
    unsigned short* A2  = (unsigned short*)d_ws;
    unsigned short* Bbt = (unsigned short*)((char*)d_ws + (size_t)(16 << 20));

    // prep: 4096 decompress blocks + 4096 cast blocks
    prep<<<O_DIM + (N_TOK * K_ACT / 8) / 256, 256, 0, stream>>>(
        weight, metadata, idx, input, (uint4*)A2, (uint4*)Bbt);

    dim3 grid(N_TOK / 128, O_DIM / 128);  // (32, 32)
    gemm_scatter<<<grid, 256, 0, stream>>>(A2, Bbt, indices, out);
}

// Round 6
// 281.099 us; speedup vs baseline: 1.0924x; 1.0924x over previous
//
#include <hip/hip_runtime.h>
#include <hip/hip_bf16.h>
#include <stdint.h>

// Problem constants (from reference)
#define O_DIM   4096
#define I_DIM   2048
#define M_DENSE 8192
#define K_DENSE 4096
#define N_TOK   4096
#define K_ACT   2048

typedef __bf16 bf16x8 __attribute__((ext_vector_type(8)));
typedef float  f32x4  __attribute__((ext_vector_type(4)));

// round-to-nearest-even fp32 -> bf16 bits
__device__ __forceinline__ unsigned f2bf(float f) {
    unsigned u = __builtin_bit_cast(unsigned, f);
    return (u + 0x7FFFu + ((u >> 16) & 1u)) >> 16;
}

// async global->LDS, 16 bytes per lane; LDS dest = wave-uniform base + lane*16
__device__ __forceinline__ void load16(const unsigned short* g, unsigned short* l) {
    __builtin_amdgcn_global_load_lds(
        (__attribute__((address_space(1))) void*)(g),
        (__attribute__((address_space(3))) void*)(l),
        16, 0, 0);
}

// Zero only the INACTIVE dense output rows (gaps in sorted `indices`):
// block b zeroes rows in (indices[b-1], indices[b]). Coalesced float4 stores.
__global__ void zero_inactive(const int* __restrict__ indices, float4* __restrict__ out4) {
    int b = blockIdx.x;                                  // 0 .. O_DIM
    int lo = (b == 0) ? -1 : indices[b - 1];             // broadcast load
    int hi = (b == O_DIM) ? M_DENSE : indices[b];
    for (int row = lo + 1; row < hi; ++row) {
        float4* dst = out4 + (size_t)row * (N_TOK / 4);
        for (int c = threadIdx.x; c < N_TOK / 4; c += 256)
            dst[c] = float4{0.f, 0.f, 0.f, 0.f};
    }
}

// Merged prep: blocks [0,O_DIM) decompress weights, blocks [O_DIM, O_DIM+4096) cast input.
__global__ __launch_bounds__(256) void prep(const float* __restrict__ weight,
                                            const int* __restrict__ metadata,
                                            const int* __restrict__ idx,
                                            const float* __restrict__ input,
                                            uint4* __restrict__ A2,
                                            uint4* __restrict__ Bbt) {
    if (blockIdx.x >= O_DIM) {
        // ---- cast branch: fp32 [N_TOK x K_ACT] -> bf16 bits (B^T layout) ----
        int gid = (blockIdx.x - O_DIM) * 256 + threadIdx.x;  // 4096 blocks
        const float4* in = (const float4*)input;
        float4 a = in[2 * gid], b = in[2 * gid + 1];
        uint4 u;
        u.x = f2bf(a.x) | (f2bf(a.y) << 16);
        u.y = f2bf(a.z) | (f2bf(a.w) << 16);
        u.z = f2bf(b.x) | (f2bf(b.y) << 16);
        u.w = f2bf(b.z) | (f2bf(b.w) << 16);
        Bbt[gid] = u;
        return;
    }
    // ---- decompress branch: A2[o][j] = weight value for active col idx[j] ----
    __shared__ int   smeta[I_DIM];
    __shared__ float sw[I_DIM];
    int o = blockIdx.x;
    const int4*   mrow = (const int4*)(metadata + (size_t)o * I_DIM);
    const float4* wrow = (const float4*)(weight + (size_t)o * I_DIM);
#pragma unroll
    for (int it = 0; it < I_DIM / 4 / 256; ++it) {
        int i = it * 256 + threadIdx.x;
        *(int4*)(smeta + i * 4) = mrow[i];
        *(float4*)(sw + i * 4)  = wrow[i];
    }
    __syncthreads();
    int j0 = threadIdx.x * 8;                            // 256 threads * 8 = K_ACT
    int4 c0 = *(const int4*)(idx + j0);
    int4 c1 = *(const int4*)(idx + j0 + 4);
    int cs[8] = {c0.x, c0.y, c0.z, c0.w, c1.x, c1.y, c1.z, c1.w};
    unsigned r[8];
#pragma unroll
    for (int u = 0; u < 8; ++u) {
        int c = cs[u];
        int g2 = (c >> 2) * 2;
        int pos = c & 3;
        int m0v = smeta[g2], m1v = smeta[g2 + 1];
        float v = (m0v == pos) ? sw[g2] : ((m1v == pos) ? sw[g2 + 1] : 0.0f);
        r[u] = f2bf(v);
    }
    uint4 packed;
    packed.x = r[0] | (r[1] << 16);
    packed.y = r[2] | (r[3] << 16);
    packed.z = r[4] | (r[5] << 16);
    packed.w = r[6] | (r[7] << 16);
    A2[((size_t)o * K_ACT + j0) >> 3] = packed;
}

// GEMM: C[o][t] = sum_j A2[o][j] * Bt[t][j]; rows scattered to out[indices[o]].
// M=4096, N=4096, K=2048. 128x128 tile, BK=64, 4 waves, 16x16x32 bf16 MFMA.
// Zero-bank-conflict layout (R5-verified: SQ_LDS_BANK_CONFLICT=0): 128B LDS
// rows span all 32 banks; k-segments XOR-swizzled by row&7.
// Slim addressing (fixes R5's spills): staging chunk f=q*256+t has
// r = q*32+(t>>3), and r&7 = (t>>3)&7 is q-INDEPENDENT, so all 8 staging
// addresses derive from 2 base pointers + uniform strides q*32*K / q*2048.
__global__ __launch_bounds__(256, 4) void gemm_scatter(
        const unsigned short* __restrict__ A,
        const unsigned short* __restrict__ Bt,
        const int* __restrict__ indices,
        float* __restrict__ out) {
    constexpr int N = N_TOK, K = K_ACT;
    constexpr int TM = 128, TN = 128, BK = 64;
    __shared__ alignas(16) unsigned short sA[TM * BK];   // 16 KB
    __shared__ alignas(16) unsigned short sB[TN * BK];   // 16 KB

    const int t    = threadIdx.x;       // 0..255
    const int wave = t >> 6;            // 0..3
    const int lane = t & 63;
    const int m0 = blockIdx.y * TM;
    const int n0 = blockIdx.x * TN;

    // staging bases: phys slot (t&7) of row r holds global k-seg (t&7)^(r&7)
    const int rbase = t >> 3;                    // row within 32-row band
    const int sseg  = (t & 7) ^ (rbase & 7);     // q-independent source seg
    const unsigned short* gA = A  + (size_t)(m0 + rbase) * K + sseg * 8;
    const unsigned short* gB = Bt + (size_t)(n0 + rbase) * K + sseg * 8;
    unsigned short* lA = sA + wave * 512;        // + q*2048 per band
    unsigned short* lB = sB + wave * 512;

    const int wm   = (wave >> 1) * 64;  // wave's 64x64 quadrant
    const int wn   = (wave & 1) * 64;
    const int quad = lane >> 4;
    const int lr   = lane & 15;
    const int lr7  = lr & 7;
    // fragment rows have row&7 == lr&7; global seg quad -> phys slot quad^lr7,
    // second k-half seg quad|4 -> phys slot ^4 -> element offset ^32.
    const int k0 = (quad ^ lr7) * 8;
    const int k1 = k0 ^ 32;

    f32x4 acc[4][4] = {};

    for (int kk = 0; kk < K; kk += BK) {
        __syncthreads();   // previous compute done before overwriting LDS
#pragma unroll
        for (int q = 0; q < 4; ++q) {
            load16(gA + (size_t)q * (32 * K) + kk, lA + q * 2048);
            load16(gB + (size_t)q * (32 * K) + kk, lB + q * 2048);
        }
        __syncthreads();   // drains vmcnt before barrier

        bf16x8 af[4], bf[4];
        // ---- k-half 0 (k 0..31 of this BK) ----
#pragma unroll
        for (int mi = 0; mi < 4; ++mi)
            af[mi] = *(const bf16x8*)(sA + (wm + mi * 16 + lr) * BK + k0);
#pragma unroll
        for (int ni = 0; ni < 4; ++ni)
            bf[ni] = *(const bf16x8*)(sB + (wn + ni * 16 + lr) * BK + k0);
#pragma unroll
        for (int mi = 0; mi < 4; ++mi)
#pragma unroll
            for (int ni = 0; ni < 4; ++ni)
                acc[mi][ni] = __builtin_amdgcn_mfma_f32_16x16x32_bf16(
                    af[mi], bf[ni], acc[mi][ni], 0, 0, 0);
        // ---- k-half 1 (k 32..63) ----
#pragma unroll
        for (int mi = 0; mi < 4; ++mi)
            af[mi] = *(const bf16x8*)(sA + (wm + mi * 16 + lr) * BK + k1);
#pragma unroll
        for (int ni = 0; ni < 4; ++ni)
            bf[ni] = *(const bf16x8*)(sB + (wn + ni * 16 + lr) * BK + k1);
#pragma unroll
        for (int mi = 0; mi < 4; ++mi)
#pragma unroll
            for (int ni = 0; ni < 4; ++ni)
                acc[mi][ni] = __builtin_amdgcn_mfma_f32_16x16x32_bf16(
                    af[mi], bf[ni], acc[mi][ni], 0, 0, 0);
    }

    // epilogue: D lane layout col=lane&15, row=quad*4+reg (m91-verified)
#pragma unroll
    for (int mi = 0; mi < 4; ++mi) {
#pragma unroll
        for (int r = 0; r < 4; ++r) {
            int gm = m0 + wm + mi * 16 + quad * 4 + r;
            int orow = indices[gm];
            float* op = out + (size_t)orow * N + n0 + wn + lr;
#pragma unroll
            for (int ni = 0; ni < 4; ++ni)
                op[ni * 16] = acc[mi][ni][r];
        }
    }
}

extern "C" void kernel_launch(void* const* d_in, const int* in_sizes, int n_in,
                              void* d_out, int out_size, void* d_ws, size_t ws_size,
                              hipStream_t stream) {
    const float* input    = (const float*)d_in[0];
    const int*   idx      = (const int*)d_in[1];
    const float* weight   = (const float*)d_in[2];
    const int*   indices  = (const int*)d_in[3];
    const int*   metadata = (const int*)d_in[4];
    float* out = (float*)d_out;

    // workspace layout: A2 (16 MB) | Bbt (16 MB)
    unsigned short* A2  = (unsigned short*)d_ws;
    unsigned short* Bbt = (unsigned short*)((char*)d_ws + (size_t)(16 << 20));

    zero_inactive<<<O_DIM + 1, 256, 0, stream>>>(indices, (float4*)out);
    // prep: 4096 decompress blocks + 4096 cast blocks
    prep<<<O_DIM + (N_TOK * K_ACT / 8) / 256, 256, 0, stream>>>(
        weight, metadata, idx, input, (uint4*)A2, (uint4*)Bbt);

    dim3 grid(N_TOK / 128, O_DIM / 128);  // (32, 32)
    gemm_scatter<<<grid, 256, 0, stream>>>(A2, Bbt, indices, out);
}